// Round 3
// baseline (327.215 us; speedup 1.0000x reference)
//
#include <hip/hip_runtime.h>

#define Bn 4096
#define En 1024
#define On 16
#define Hn 1024

#define BM 64
#define BN 128
#define BK 64

using floatx4 = __attribute__((ext_vector_type(4))) float;
using float4v = __attribute__((ext_vector_type(4))) float;
using bf16x8  = __attribute__((ext_vector_type(8))) __bf16;
using short4v = __attribute__((ext_vector_type(4))) short;
using short8v = __attribute__((ext_vector_type(8))) short;

__device__ inline unsigned short f2bf(float f) {
    unsigned u = __builtin_bit_cast(unsigned, f);
    u += 0x7fffu + ((u >> 16) & 1u);   // RNE to bf16 (inputs finite)
    return (unsigned short)(u >> 16);
}

// async global->LDS, 16B per lane; LDS dest is wave-uniform base + lane*16
#define GLOAD16(gp, lp) __builtin_amdgcn_global_load_lds( \
    (const __attribute__((address_space(1))) unsigned int*)(gp), \
    (__attribute__((address_space(3))) unsigned int*)(lp), 16, 0, 0)

// ---------------- bucket examples by op ----------------
__global__ void bucket_kernel(const int* __restrict__ op_idx,
                              int* __restrict__ sorted_idx,
                              int* __restrict__ offsets) {
    __shared__ int cnt[On], cur[On], off[On + 1];
    int tid = threadIdx.x;
    if (tid < On) { cnt[tid] = 0; cur[tid] = 0; }
    __syncthreads();
    for (int i = tid; i < Bn; i += blockDim.x) atomicAdd(&cnt[op_idx[i]], 1);
    __syncthreads();
    if (tid == 0) {
        int s = 0;
        for (int o = 0; o < On; ++o) { off[o] = s; s += cnt[o]; }
        off[On] = s;
    }
    __syncthreads();
    for (int i = tid; i < Bn; i += blockDim.x) {
        int o = op_idx[i];
        int p = off[o] + atomicAdd(&cur[o], 1);
        sorted_idx[p] = i;
    }
    if (tid <= On) offsets[tid] = off[tid];
}

// ---------------- W[e][o][h] fp32 -> Wt[o][h][e] bf16 (64x64 LDS tile) ----------------
__global__ __launch_bounds__(256) void wtrans_kernel(const float* __restrict__ W,
                                                     unsigned short* __restrict__ Wt) {
    __shared__ float tile[64][65];
    int o = blockIdx.z, e0 = blockIdx.y * 64, h0 = blockIdx.x * 64;
    int t = threadIdx.x;
    int er = t >> 4, c4 = (t & 15) * 4;
#pragma unroll
    for (int r = 0; r < 4; ++r) {
        const float* p = W + ((size_t)(e0 + er + 16 * r) * On + o) * Hn + h0 + c4;
        *(float4v*)&tile[er + 16 * r][c4] = *(const float4v*)p;
    }
    __syncthreads();
    int hr = t >> 3, e8 = (t & 7) * 8;
#pragma unroll
    for (int r = 0; r < 2; ++r) {
        short8v v;
#pragma unroll
        for (int j = 0; j < 8; ++j) v[j] = (short)f2bf(tile[e8 + j][hr + 32 * r]);
        *(short8v*)(Wt + ((size_t)o * Hn + (h0 + hr + 32 * r)) * En + e0 + e8) = v;
    }
}

// ---------------- gather + cvt x -> xs[sorted][k] bf16 ----------------
__global__ __launch_bounds__(256) void xprep_kernel(const float* __restrict__ x,
                                                    const int* __restrict__ sorted_idx,
                                                    unsigned short* __restrict__ xs) {
    int row = blockIdx.x;
    int src = sorted_idx[row];
    int t = threadIdx.x;
    float4v f = *(const float4v*)(x + (size_t)src * En + t * 4);
    short4v v = { (short)f2bf(f[0]), (short)f2bf(f[1]),
                  (short)f2bf(f[2]), (short)f2bf(f[3]) };
    *(short4v*)(xs + (size_t)row * En + t * 4) = v;
}

// ---------------- layer 1: h1 = relu(xs @ Wt1[o]^T + b1[o]) ----------------
__global__ __launch_bounds__(256) void gemm1_kernel(
    const unsigned short* __restrict__ xs, const unsigned short* __restrict__ Wt,
    const float* __restrict__ bias1, const int* __restrict__ offsets,
    unsigned short* __restrict__ h1) {
    int o = blockIdx.z;
    int off = offsets[o], cnt = offsets[o + 1] - off;
    int m0 = blockIdx.y * BM;
    if (m0 >= cnt) return;
    int n0 = blockIdx.x * BN;

    __shared__ unsigned short As[8][BM][8];   // 8 KB, granule-major
    __shared__ unsigned short Bs[8][BN][8];   // 16 KB

    int tid = threadIdx.x, lane = tid & 63, wave = tid >> 6;
    const unsigned short* Abase = xs + (size_t)(off + m0) * En;
    const unsigned short* Bbase = Wt + ((size_t)o * Hn + n0) * En;

    floatx4 acc[2][4] = {};
    int wm = (wave >> 1) * 32, wn = (wave & 1) * 64;
    int l15 = lane & 15, kg = lane >> 4;

    for (int kt = 0; kt < En; kt += BK) {
        // A: wave stages granules g=wave*2+{0,1}; lane covers row=lane
#pragma unroll
        for (int i = 0; i < 2; ++i) {
            int g = wave * 2 + i;
            GLOAD16(Abase + (size_t)lane * En + kt + g * 8, &As[g][0][0]);
        }
        // B: wave stages idx=wave*4+{0..3}: g=idx>>1, n-half=idx&1
#pragma unroll
        for (int i = 0; i < 4; ++i) {
            int idx = wave * 4 + i;
            int g = idx >> 1, half = idx & 1;
            GLOAD16(Bbase + (size_t)(half * 64 + lane) * En + kt + g * 8,
                    &Bs[g][half * 64][0]);
        }
        __syncthreads();
#pragma unroll
        for (int ks = 0; ks < 2; ++ks) {
            int g = ks * 4 + kg;
            bf16x8 af[2], bfr[4];
#pragma unroll
            for (int mt = 0; mt < 2; ++mt) af[mt] = *(const bf16x8*)&As[g][wm + mt * 16 + l15][0];
#pragma unroll
            for (int nt = 0; nt < 4; ++nt) bfr[nt] = *(const bf16x8*)&Bs[g][wn + nt * 16 + l15][0];
#pragma unroll
            for (int mt = 0; mt < 2; ++mt)
#pragma unroll
                for (int nt = 0; nt < 4; ++nt)
                    acc[mt][nt] = __builtin_amdgcn_mfma_f32_16x16x32_bf16(af[mt], bfr[nt], acc[mt][nt], 0, 0, 0);
        }
        __syncthreads();
    }

    int r4 = (lane >> 4) * 4;
#pragma unroll
    for (int nt = 0; nt < 4; ++nt) {
        int col = n0 + wn + nt * 16 + l15;
        float bv = bias1[o * Hn + col];
#pragma unroll
        for (int mt = 0; mt < 2; ++mt) {
#pragma unroll
            for (int r = 0; r < 4; ++r) {
                int row = m0 + wm + mt * 16 + r4 + r;
                if (row < cnt) {
                    float v = acc[mt][nt][r] + bv;
                    v = v > 0.f ? v : 0.f;
                    h1[(size_t)(off + row) * Hn + col] = f2bf(v);
                }
            }
        }
    }
}

// ---------------- layer 2: out[sel] = relu(h1 @ Wt2[o]^T + b2[o]) ----------------
__global__ __launch_bounds__(256) void gemm2_kernel(
    const unsigned short* __restrict__ h1, const unsigned short* __restrict__ Wt,
    const float* __restrict__ bias2, const int* __restrict__ sorted_idx,
    const int* __restrict__ offsets, float* __restrict__ out) {
    int o = blockIdx.z;
    int off = offsets[o], cnt = offsets[o + 1] - off;
    int m0 = blockIdx.y * BM;
    if (m0 >= cnt) return;
    int n0 = blockIdx.x * BN;

    __shared__ unsigned short As[8][BM][8];
    __shared__ unsigned short Bs[8][BN][8];

    int tid = threadIdx.x, lane = tid & 63, wave = tid >> 6;
    const unsigned short* Abase = h1 + (size_t)(off + m0) * Hn;
    const unsigned short* Bbase = Wt + ((size_t)o * Hn + n0) * Hn;

    floatx4 acc[2][4] = {};
    int wm = (wave >> 1) * 32, wn = (wave & 1) * 64;
    int l15 = lane & 15, kg = lane >> 4;

    for (int kt = 0; kt < Hn; kt += BK) {
#pragma unroll
        for (int i = 0; i < 2; ++i) {
            int g = wave * 2 + i;
            GLOAD16(Abase + (size_t)lane * Hn + kt + g * 8, &As[g][0][0]);
        }
#pragma unroll
        for (int i = 0; i < 4; ++i) {
            int idx = wave * 4 + i;
            int g = idx >> 1, half = idx & 1;
            GLOAD16(Bbase + (size_t)(half * 64 + lane) * Hn + kt + g * 8,
                    &Bs[g][half * 64][0]);
        }
        __syncthreads();
#pragma unroll
        for (int ks = 0; ks < 2; ++ks) {
            int g = ks * 4 + kg;
            bf16x8 af[2], bfr[4];
#pragma unroll
            for (int mt = 0; mt < 2; ++mt) af[mt] = *(const bf16x8*)&As[g][wm + mt * 16 + l15][0];
#pragma unroll
            for (int nt = 0; nt < 4; ++nt) bfr[nt] = *(const bf16x8*)&Bs[g][wn + nt * 16 + l15][0];
#pragma unroll
            for (int mt = 0; mt < 2; ++mt)
#pragma unroll
                for (int nt = 0; nt < 4; ++nt)
                    acc[mt][nt] = __builtin_amdgcn_mfma_f32_16x16x32_bf16(af[mt], bfr[nt], acc[mt][nt], 0, 0, 0);
        }
        __syncthreads();
    }

    int r4 = (lane >> 4) * 4;
    float bv[4];
#pragma unroll
    for (int nt = 0; nt < 4; ++nt) bv[nt] = bias2[o * Hn + n0 + wn + nt * 16 + l15];
#pragma unroll
    for (int mt = 0; mt < 2; ++mt) {
#pragma unroll
        for (int r = 0; r < 4; ++r) {
            int row = m0 + wm + mt * 16 + r4 + r;
            if (row < cnt) {
                int b = sorted_idx[off + row];
                float* orow = out + (size_t)b * Hn + n0 + wn + l15;
#pragma unroll
                for (int nt = 0; nt < 4; ++nt) {
                    float v = acc[mt][nt][r] + bv[nt];
                    orow[nt * 16] = v > 0.f ? v : 0.f;
                }
            }
        }
    }
}

extern "C" void kernel_launch(void* const* d_in, const int* in_sizes, int n_in,
                              void* d_out, int out_size, void* d_ws, size_t ws_size,
                              hipStream_t stream) {
    const float* x      = (const float*)d_in[0];
    const int*   op_idx = (const int*)d_in[1];
    const float* W1     = (const float*)d_in[2];
    const float* bias1  = (const float*)d_in[3];
    const float* W2     = (const float*)d_in[4];
    const float* bias2  = (const float*)d_in[5];
    float* out = (float*)d_out;

    char* ws = (char*)d_ws;
    int* offsets    = (int*)ws;                                   // 68 B
    int* sorted_idx = (int*)(ws + 1024);                          // 16 KB
    unsigned short* xs = (unsigned short*)(ws + 65536);           // 8 MB bf16 [4096][1024]
    unsigned short* h1 = (unsigned short*)(ws + 65536 + 8388608); // 8 MB bf16
    unsigned short* Wt = (unsigned short*)(ws + 65536 + 16777216);// 32 MB bf16 [16][1024][1024]

    dim3 tgrid(Hn / 64, En / 64, On);
    hipLaunchKernelGGL(wtrans_kernel, tgrid, dim3(256), 0, stream, W1, Wt);
    hipLaunchKernelGGL(bucket_kernel, dim3(1), dim3(1024), 0, stream,
                       op_idx, sorted_idx, offsets);
    hipLaunchKernelGGL(xprep_kernel, dim3(Bn), dim3(256), 0, stream,
                       x, sorted_idx, xs);
    dim3 grid(Hn / BN, Bn / BM, On);
    hipLaunchKernelGGL(gemm1_kernel, grid, dim3(256), 0, stream,
                       xs, Wt, bias1, offsets, h1);
    hipLaunchKernelGGL(wtrans_kernel, tgrid, dim3(256), 0, stream, W2, Wt);
    hipLaunchKernelGGL(gemm2_kernel, grid, dim3(256), 0, stream,
                       h1, Wt, bias2, sorted_idx, offsets, out);
}

// Round 4
// 315.434 us; speedup vs baseline: 1.0373x; 1.0373x over previous
//
#include <hip/hip_runtime.h>

#define Bn 4096
#define En 1024
#define On 16
#define Hn 1024

#define BM 64
#define BN 64
#define BK 64

using floatx4 = __attribute__((ext_vector_type(4))) float;
using float4v = __attribute__((ext_vector_type(4))) float;
using bf16x8  = __attribute__((ext_vector_type(8))) __bf16;
using short4v = __attribute__((ext_vector_type(4))) short;
using short8v = __attribute__((ext_vector_type(8))) short;

__device__ inline unsigned short f2bf(float f) {
    unsigned u = __builtin_bit_cast(unsigned, f);
    u += 0x7fffu + ((u >> 16) & 1u);   // RNE to bf16 (inputs finite)
    return (unsigned short)(u >> 16);
}

// async global->LDS, 16B per lane; LDS dest = wave-uniform base + lane*16
#define GLOAD16(gp, lp) __builtin_amdgcn_global_load_lds( \
    (const __attribute__((address_space(1))) unsigned int*)(gp), \
    (__attribute__((address_space(3))) unsigned int*)(lp), 16, 0, 0)

// ---------------- W[e][o][h] fp32 -> Wt[o][h][e] bf16; z==On slice runs bucket ----------------
__global__ __launch_bounds__(256) void wtrans_kernel(const float* __restrict__ W,
                                                     unsigned short* __restrict__ Wt,
                                                     const int* __restrict__ op_idx,
                                                     int* __restrict__ sorted_idx,
                                                     int* __restrict__ offsets) {
    if (blockIdx.z == On) {
        if (blockIdx.x != 0 || blockIdx.y != 0) return;
        __shared__ int cnt[On], cur[On], off[On + 1];
        int tid = threadIdx.x;
        if (tid < On) { cnt[tid] = 0; cur[tid] = 0; }
        __syncthreads();
        for (int i = tid; i < Bn; i += 256) atomicAdd(&cnt[op_idx[i]], 1);
        __syncthreads();
        if (tid == 0) {
            int s = 0;
            for (int o = 0; o < On; ++o) { off[o] = s; s += cnt[o]; }
            off[On] = s;
        }
        __syncthreads();
        for (int i = tid; i < Bn; i += 256) {
            int o = op_idx[i];
            sorted_idx[off[o] + atomicAdd(&cur[o], 1)] = i;
        }
        if (tid <= On) offsets[tid] = off[tid];
        return;
    }
    __shared__ float tile[64][65];
    int o = blockIdx.z, e0 = blockIdx.y * 64, h0 = blockIdx.x * 64;
    int t = threadIdx.x;
    int er = t >> 4, c4 = (t & 15) * 4;
#pragma unroll
    for (int r = 0; r < 4; ++r) {
        const float* p = W + ((size_t)(e0 + er + 16 * r) * On + o) * Hn + h0 + c4;
        *(float4v*)&tile[er + 16 * r][c4] = *(const float4v*)p;
    }
    __syncthreads();
    int hr = t >> 3, e8 = (t & 7) * 8;
#pragma unroll
    for (int r = 0; r < 2; ++r) {
        short8v v;
#pragma unroll
        for (int j = 0; j < 8; ++j) v[j] = (short)f2bf(tile[e8 + j][hr + 32 * r]);
        *(short8v*)(Wt + ((size_t)o * Hn + (h0 + hr + 32 * r)) * En + e0 + e8) = v;
    }
}

// ---------------- gather + cvt x -> xs[sorted][k] bf16 ----------------
__global__ __launch_bounds__(256) void xprep_kernel(const float* __restrict__ x,
                                                    const int* __restrict__ sorted_idx,
                                                    unsigned short* __restrict__ xs) {
    int t = threadIdx.x;
#pragma unroll 4
    for (int r = 0; r < 16; ++r) {
        int row = blockIdx.x * 16 + r;
        int src = sorted_idx[row];
        float4v f = *(const float4v*)(x + (size_t)src * En + t * 4);
        short4v v = { (short)f2bf(f[0]), (short)f2bf(f[1]),
                      (short)f2bf(f[2]), (short)f2bf(f[3]) };
        *(short4v*)(xs + (size_t)row * En + t * 4) = v;
    }
}

// ---------------- layer 1: h1 = relu(xs @ Wt1[o]^T + b1[o]), double-buffered ----------------
__global__ __launch_bounds__(256, 4) void gemm1_kernel(
    const unsigned short* __restrict__ xs, const unsigned short* __restrict__ Wt,
    const float* __restrict__ bias1, const int* __restrict__ offsets,
    unsigned short* __restrict__ h1) {
    int o = blockIdx.z;
    int off = offsets[o], cnt = offsets[o + 1] - off;
    int m0 = blockIdx.y * BM;
    if (m0 >= cnt) return;
    int n0 = blockIdx.x * BN;

    __shared__ unsigned short As[2][8][BM][8];   // 2 x 8 KB
    __shared__ unsigned short Bs[2][8][BN][8];   // 2 x 8 KB

    int tid = threadIdx.x, lane = tid & 63, wave = tid >> 6;
    const unsigned short* Abase = xs + (size_t)(off + m0 + lane) * En;
    const unsigned short* Bbase = Wt + ((size_t)o * Hn + n0 + lane) * En;

    floatx4 acc[2][2] = {};
    int wm = (wave >> 1) * 32, wn = (wave & 1) * 32;
    int l15 = lane & 15, kg = lane >> 4;

    // prologue: stage iter 0 into buf 0
#pragma unroll
    for (int i = 0; i < 2; ++i) {
        int g = wave + i * 4;
        GLOAD16(Abase + g * 8, &As[0][g][0][0]);
        GLOAD16(Bbase + g * 8, &Bs[0][g][0][0]);
    }

    for (int it = 0; it < En / BK; ++it) {
        int cur = it & 1;
        __syncthreads();   // drains loads issued last iter (buf cur) + prior ds_reads
        if (it + 1 < En / BK) {
            int kt = (it + 1) * BK;
#pragma unroll
            for (int i = 0; i < 2; ++i) {
                int g = wave + i * 4;
                GLOAD16(Abase + kt + g * 8, &As[cur ^ 1][g][0][0]);
                GLOAD16(Bbase + kt + g * 8, &Bs[cur ^ 1][g][0][0]);
            }
        }
#pragma unroll
        for (int ks = 0; ks < 2; ++ks) {
            int g = ks * 4 + kg;
            bf16x8 af[2], bfr[2];
#pragma unroll
            for (int mt = 0; mt < 2; ++mt) af[mt] = *(const bf16x8*)&As[cur][g][wm + mt * 16 + l15][0];
#pragma unroll
            for (int nt = 0; nt < 2; ++nt) bfr[nt] = *(const bf16x8*)&Bs[cur][g][wn + nt * 16 + l15][0];
#pragma unroll
            for (int mt = 0; mt < 2; ++mt)
#pragma unroll
                for (int nt = 0; nt < 2; ++nt)
                    acc[mt][nt] = __builtin_amdgcn_mfma_f32_16x16x32_bf16(af[mt], bfr[nt], acc[mt][nt], 0, 0, 0);
        }
    }

    int r4 = kg * 4;
#pragma unroll
    for (int nt = 0; nt < 2; ++nt) {
        int col = n0 + wn + nt * 16 + l15;
        float bv = bias1[o * Hn + col];
#pragma unroll
        for (int mt = 0; mt < 2; ++mt) {
#pragma unroll
            for (int r = 0; r < 4; ++r) {
                int row = m0 + wm + mt * 16 + r4 + r;
                if (row < cnt) {
                    float v = acc[mt][nt][r] + bv;
                    h1[(size_t)(off + row) * Hn + col] = f2bf(v > 0.f ? v : 0.f);
                }
            }
        }
    }
}

// ---------------- layer 2: out[sel] = relu(h1 @ Wt2[o]^T + b2[o]), double-buffered ----------------
__global__ __launch_bounds__(256, 4) void gemm2_kernel(
    const unsigned short* __restrict__ h1, const unsigned short* __restrict__ Wt,
    const float* __restrict__ bias2, const int* __restrict__ sorted_idx,
    const int* __restrict__ offsets, float* __restrict__ out) {
    int o = blockIdx.z;
    int off = offsets[o], cnt = offsets[o + 1] - off;
    int m0 = blockIdx.y * BM;
    if (m0 >= cnt) return;
    int n0 = blockIdx.x * BN;

    __shared__ unsigned short As[2][8][BM][8];
    __shared__ unsigned short Bs[2][8][BN][8];

    int tid = threadIdx.x, lane = tid & 63, wave = tid >> 6;
    const unsigned short* Abase = h1 + (size_t)(off + m0 + lane) * Hn;
    const unsigned short* Bbase = Wt + ((size_t)o * Hn + n0 + lane) * Hn;

    floatx4 acc[2][2] = {};
    int wm = (wave >> 1) * 32, wn = (wave & 1) * 32;
    int l15 = lane & 15, kg = lane >> 4;

#pragma unroll
    for (int i = 0; i < 2; ++i) {
        int g = wave + i * 4;
        GLOAD16(Abase + g * 8, &As[0][g][0][0]);
        GLOAD16(Bbase + g * 8, &Bs[0][g][0][0]);
    }

    for (int it = 0; it < Hn / BK; ++it) {
        int cur = it & 1;
        __syncthreads();
        if (it + 1 < Hn / BK) {
            int kt = (it + 1) * BK;
#pragma unroll
            for (int i = 0; i < 2; ++i) {
                int g = wave + i * 4;
                GLOAD16(Abase + kt + g * 8, &As[cur ^ 1][g][0][0]);
                GLOAD16(Bbase + kt + g * 8, &Bs[cur ^ 1][g][0][0]);
            }
        }
#pragma unroll
        for (int ks = 0; ks < 2; ++ks) {
            int g = ks * 4 + kg;
            bf16x8 af[2], bfr[2];
#pragma unroll
            for (int mt = 0; mt < 2; ++mt) af[mt] = *(const bf16x8*)&As[cur][g][wm + mt * 16 + l15][0];
#pragma unroll
            for (int nt = 0; nt < 2; ++nt) bfr[nt] = *(const bf16x8*)&Bs[cur][g][wn + nt * 16 + l15][0];
#pragma unroll
            for (int mt = 0; mt < 2; ++mt)
#pragma unroll
                for (int nt = 0; nt < 2; ++nt)
                    acc[mt][nt] = __builtin_amdgcn_mfma_f32_16x16x32_bf16(af[mt], bfr[nt], acc[mt][nt], 0, 0, 0);
        }
    }

    int r4 = kg * 4;
    float bv[2];
#pragma unroll
    for (int nt = 0; nt < 2; ++nt) bv[nt] = bias2[o * Hn + n0 + wn + nt * 16 + l15];
#pragma unroll
    for (int mt = 0; mt < 2; ++mt) {
#pragma unroll
        for (int r = 0; r < 4; ++r) {
            int row = m0 + wm + mt * 16 + r4 + r;
            if (row < cnt) {
                int b = sorted_idx[off + row];
                float* orow = out + (size_t)b * Hn + n0 + wn + l15;
#pragma unroll
                for (int nt = 0; nt < 2; ++nt) {
                    float v = acc[mt][nt][r] + bv[nt];
                    orow[nt * 16] = v > 0.f ? v : 0.f;
                }
            }
        }
    }
}

extern "C" void kernel_launch(void* const* d_in, const int* in_sizes, int n_in,
                              void* d_out, int out_size, void* d_ws, size_t ws_size,
                              hipStream_t stream) {
    const float* x      = (const float*)d_in[0];
    const int*   op_idx = (const int*)d_in[1];
    const float* W1     = (const float*)d_in[2];
    const float* bias1  = (const float*)d_in[3];
    const float* W2     = (const float*)d_in[4];
    const float* bias2  = (const float*)d_in[5];
    float* out = (float*)d_out;

    char* ws = (char*)d_ws;
    int* offsets    = (int*)ws;                                   // 68 B
    int* sorted_idx = (int*)(ws + 1024);                          // 16 KB
    unsigned short* xs = (unsigned short*)(ws + 65536);           // 8 MB
    unsigned short* h1 = (unsigned short*)(ws + 65536 + 8388608); // 8 MB
    unsigned short* Wt = (unsigned short*)(ws + 65536 + 16777216);// 32 MB

    // K1: W1 transpose + bucket (fused via extra z slice)
    hipLaunchKernelGGL(wtrans_kernel, dim3(Hn / 64, En / 64, On + 1), dim3(256), 0, stream,
                       W1, Wt, op_idx, sorted_idx, offsets);
    // K2: gather + cvt x
    hipLaunchKernelGGL(xprep_kernel, dim3(Bn / 16), dim3(256), 0, stream,
                       x, sorted_idx, xs);
    // K3: layer-1 GEMM
    dim3 grid(Hn / BN, Bn / BM, On);
    hipLaunchKernelGGL(gemm1_kernel, grid, dim3(256), 0, stream,
                       xs, Wt, bias1, offsets, h1);
    // K4: W2 transpose (reuses Wt)
    hipLaunchKernelGGL(wtrans_kernel, dim3(Hn / 64, Hn / 64, On), dim3(256), 0, stream,
                       W2, Wt, op_idx, sorted_idx, offsets);
    // K5: layer-2 GEMM
    hipLaunchKernelGGL(gemm2_kernel, grid, dim3(256), 0, stream,
                       h1, Wt, bias2, sorted_idx, offsets, out);
}

// Round 5
// 284.637 us; speedup vs baseline: 1.1496x; 1.1082x over previous
//
#include <hip/hip_runtime.h>

#define Bn 4096
#define En 1024
#define On 16
#define Hn 1024
#define MT 80            // max padded m-tiles (64 rows each)

using floatx4 = __attribute__((ext_vector_type(4))) float;
using float4v = __attribute__((ext_vector_type(4))) float;
using bf16x8  = __attribute__((ext_vector_type(8))) __bf16;
using short8v = __attribute__((ext_vector_type(8))) short;

__device__ inline unsigned short f2bf(float f) {
    unsigned u = __builtin_bit_cast(unsigned, f);
    u += 0x7fffu + ((u >> 16) & 1u);   // RNE (inputs finite)
    return (unsigned short)(u >> 16);
}

// async global->LDS, 16B/lane; LDS dest = wave-uniform base + lane*16
#define GLOAD16(gp, lp) __builtin_amdgcn_global_load_lds( \
    (const __attribute__((address_space(1))) unsigned int*)(gp), \
    (__attribute__((address_space(3))) unsigned int*)(lp), 16, 0, 0)

// ---- W[e][o][h] fp32 -> Wt tiled [o][nb 8][gg 128][row 128][8] bf16; z==On slice: bucket ----
__global__ __launch_bounds__(256) void wtrans_kernel(const float* __restrict__ W,
                                                     unsigned short* __restrict__ Wt,
                                                     const int* __restrict__ op_idx,
                                                     int* __restrict__ sidx_pad,
                                                     int* __restrict__ offs) {
    if (blockIdx.z == On) {   // bucket + padded offsets
        if (blockIdx.x != 0 || blockIdx.y != 0) return;
        __shared__ int cnt[On], cur[On], po[On + 1];
        int tid = threadIdx.x;
        if (tid < On) { cnt[tid] = 0; cur[tid] = 0; }
        __syncthreads();
        for (int i = tid; i < Bn; i += 256) atomicAdd(&cnt[op_idx[i]], 1);
        __syncthreads();
        if (tid == 0) {
            int ps = 0;
            for (int o = 0; o < On; ++o) { po[o] = ps; ps += (cnt[o] + 63) & ~63; }
            po[On] = ps;
        }
        __syncthreads();
        for (int p = tid; p < MT * 64; p += 256) sidx_pad[p] = -1;
        __syncthreads();
        for (int i = tid; i < Bn; i += 256) {
            int o = op_idx[i];
            sidx_pad[po[o] + atomicAdd(&cur[o], 1)] = i;
        }
        if (tid <= On) offs[tid] = po[tid];
        if (tid < On)  offs[20 + tid] = cnt[tid];
        return;
    }
    __shared__ float tile[64][65];
    int o = blockIdx.z, e0 = blockIdx.y * 64, h0 = blockIdx.x * 64;
    int t = threadIdx.x;
    int er = t >> 4, c4 = (t & 15) * 4;
#pragma unroll
    for (int r = 0; r < 4; ++r) {
        const float* p = W + ((size_t)(e0 + er + 16 * r) * On + o) * Hn + h0 + c4;
        *(float4v*)&tile[er + 16 * r][c4] = *(const float4v*)p;
    }
    __syncthreads();
    int row = t & 63, gl = t >> 6;
#pragma unroll
    for (int r = 0; r < 2; ++r) {
        int ggl = gl + 4 * r;            // local granule 0..7
        short8v v;
#pragma unroll
        for (int j = 0; j < 8; ++j) v[j] = (short)f2bf(tile[ggl * 8 + j][row]);
        int gg = (e0 >> 3) + ggl;
        size_t dst = ((((size_t)o * 8 + (h0 >> 7)) * 128 + gg) * 128 + ((h0 & 64) + row)) * 8;
        *(short8v*)(Wt + dst) = v;       // 64 lanes -> 1KB contiguous
    }
}

// ---- gather + cvt x -> xs tiled [mtile][gg 128][row 64][8] bf16 ----
__global__ __launch_bounds__(256) void xprep_kernel(const float* __restrict__ x,
                                                    const int* __restrict__ sidx_pad,
                                                    const int* __restrict__ offs,
                                                    unsigned short* __restrict__ xs) {
    int p0 = blockIdx.x * 64;
    if (p0 >= offs[On]) return;          // beyond total padded rows
    int t = threadIdx.x, row = t & 63, gl = t >> 6;
    int src = sidx_pad[p0 + row];
    const float* xr = (src >= 0) ? (x + (size_t)src * En) : nullptr;
    unsigned short* xbase = xs + (size_t)(p0 >> 6) * 65536 + row * 8;
#pragma unroll 4
    for (int r = 0; r < 32; ++r) {
        int gg = gl + r * 4;
        short8v v = {};
        if (xr) {
            float4v f0 = *(const float4v*)(xr + gg * 8);
            float4v f1 = *(const float4v*)(xr + gg * 8 + 4);
#pragma unroll
            for (int j = 0; j < 4; ++j) { v[j] = (short)f2bf(f0[j]); v[4 + j] = (short)f2bf(f1[j]); }
        }
        *(short8v*)(xbase + (size_t)gg * 512) = v;   // 64 lanes -> 1KB contiguous
    }
}

// ---- layer 1: h1T = relu(xs @ Wt1^T + b1), tiled in, tiled out ----
__global__ __launch_bounds__(256, 4) void gemm1_kernel(
    const unsigned short* __restrict__ xs, const unsigned short* __restrict__ Wt,
    const float* __restrict__ bias1, const int* __restrict__ offs,
    unsigned short* __restrict__ h1T) {
    int o = blockIdx.z;
    int cnt = offs[20 + o];
    int m0 = blockIdx.y * 64;
    if (m0 >= cnt) return;
    int mtile = (offs[o] >> 6) + blockIdx.y;
    int n0 = blockIdx.x * 128;

    __shared__ unsigned short As[2][8][64][8];    // 16 KB
    __shared__ unsigned short Bs[2][8][128][8];   // 32 KB

    int tid = threadIdx.x, lane = tid & 63, wave = tid >> 6;
    const unsigned short* Abase = xs + (size_t)mtile * 65536 + lane * 8;
    const unsigned short* Bbase = Wt + ((size_t)o * 8 + (n0 >> 7)) * 131072 + lane * 8;

    floatx4 acc[2][4] = {};
    int wm = (wave >> 1) * 32, wn = (wave & 1) * 64;
    int l15 = lane & 15, kg = lane >> 4;

#pragma unroll
    for (int i = 0; i < 2; ++i) { int g = wave * 2 + i; GLOAD16(Abase + g * 512, &As[0][g][0][0]); }
#pragma unroll
    for (int i = 0; i < 4; ++i) { int idx = wave * 4 + i; int g = idx >> 1, hf = idx & 1;
        GLOAD16(Bbase + g * 1024 + hf * 512, &Bs[0][g][hf * 64][0]); }

    for (int it = 0; it < 16; ++it) {
        int cur = it & 1;
        __syncthreads();
        if (it + 1 < 16) {
            int aoff = (it + 1) * 4096, boff = (it + 1) * 8192;
#pragma unroll
            for (int i = 0; i < 2; ++i) { int g = wave * 2 + i;
                GLOAD16(Abase + aoff + g * 512, &As[cur ^ 1][g][0][0]); }
#pragma unroll
            for (int i = 0; i < 4; ++i) { int idx = wave * 4 + i; int g = idx >> 1, hf = idx & 1;
                GLOAD16(Bbase + boff + g * 1024 + hf * 512, &Bs[cur ^ 1][g][hf * 64][0]); }
        }
#pragma unroll
        for (int ks = 0; ks < 2; ++ks) {
            int g = ks * 4 + kg;
            bf16x8 af[2], bfr[4];
#pragma unroll
            for (int mt = 0; mt < 2; ++mt) af[mt] = *(const bf16x8*)&As[cur][g][wm + mt * 16 + l15][0];
#pragma unroll
            for (int nt = 0; nt < 4; ++nt) bfr[nt] = *(const bf16x8*)&Bs[cur][g][wn + nt * 16 + l15][0];
#pragma unroll
            for (int mt = 0; mt < 2; ++mt)
#pragma unroll
                for (int nt = 0; nt < 4; ++nt)
                    acc[mt][nt] = __builtin_amdgcn_mfma_f32_16x16x32_bf16(af[mt], bfr[nt], acc[mt][nt], 0, 0, 0);
        }
    }
    __syncthreads();

    // epilogue: bias+relu, transpose to gemm2 A-layout via LDS, coalesced dump
    unsigned short* ep = &As[0][0][0][0];   // 16 KB = [16 ggl][64 row][8]
#pragma unroll
    for (int nt = 0; nt < 4; ++nt) {
        int col = wn + nt * 16 + l15;
        float bv = bias1[o * Hn + n0 + col];
#pragma unroll
        for (int mt = 0; mt < 2; ++mt)
#pragma unroll
            for (int r = 0; r < 4; ++r) {
                int rowl = wm + mt * 16 + kg * 4 + r;
                float v = acc[mt][nt][r] + bv;
                ep[((col >> 3) * 64 + rowl) * 8 + (col & 7)] = f2bf(v > 0.f ? v : 0.f);
            }
    }
    __syncthreads();
    unsigned short* dst = h1T + (size_t)mtile * 65536 + (size_t)(n0 >> 3) * 512;
#pragma unroll
    for (int rr = 0; rr < 4; ++rr) {
        int idx = rr * 256 + tid;
        *(short8v*)(dst + idx * 8) = *(const short8v*)(ep + idx * 8);
    }
}

// ---- layer 2: out[orig] = relu(h1T @ Wt2^T + b2), scatter epilogue ----
__global__ __launch_bounds__(256, 4) void gemm2_kernel(
    const unsigned short* __restrict__ h1T, const unsigned short* __restrict__ Wt,
    const float* __restrict__ bias2, const int* __restrict__ sidx_pad,
    const int* __restrict__ offs, float* __restrict__ out) {
    int o = blockIdx.z;
    int cnt = offs[20 + o];
    int m0 = blockIdx.y * 64;
    if (m0 >= cnt) return;
    int mtile = (offs[o] >> 6) + blockIdx.y;
    int n0 = blockIdx.x * 128;

    __shared__ unsigned short As[2][8][64][8];
    __shared__ unsigned short Bs[2][8][128][8];

    int tid = threadIdx.x, lane = tid & 63, wave = tid >> 6;
    const unsigned short* Abase = h1T + (size_t)mtile * 65536 + lane * 8;
    const unsigned short* Bbase = Wt + ((size_t)o * 8 + (n0 >> 7)) * 131072 + lane * 8;

    floatx4 acc[2][4] = {};
    int wm = (wave >> 1) * 32, wn = (wave & 1) * 64;
    int l15 = lane & 15, kg = lane >> 4;

#pragma unroll
    for (int i = 0; i < 2; ++i) { int g = wave * 2 + i; GLOAD16(Abase + g * 512, &As[0][g][0][0]); }
#pragma unroll
    for (int i = 0; i < 4; ++i) { int idx = wave * 4 + i; int g = idx >> 1, hf = idx & 1;
        GLOAD16(Bbase + g * 1024 + hf * 512, &Bs[0][g][hf * 64][0]); }

    for (int it = 0; it < 16; ++it) {
        int cur = it & 1;
        __syncthreads();
        if (it + 1 < 16) {
            int aoff = (it + 1) * 4096, boff = (it + 1) * 8192;
#pragma unroll
            for (int i = 0; i < 2; ++i) { int g = wave * 2 + i;
                GLOAD16(Abase + aoff + g * 512, &As[cur ^ 1][g][0][0]); }
#pragma unroll
            for (int i = 0; i < 4; ++i) { int idx = wave * 4 + i; int g = idx >> 1, hf = idx & 1;
                GLOAD16(Bbase + boff + g * 1024 + hf * 512, &Bs[cur ^ 1][g][hf * 64][0]); }
        }
#pragma unroll
        for (int ks = 0; ks < 2; ++ks) {
            int g = ks * 4 + kg;
            bf16x8 af[2], bfr[4];
#pragma unroll
            for (int mt = 0; mt < 2; ++mt) af[mt] = *(const bf16x8*)&As[cur][g][wm + mt * 16 + l15][0];
#pragma unroll
            for (int nt = 0; nt < 4; ++nt) bfr[nt] = *(const bf16x8*)&Bs[cur][g][wn + nt * 16 + l15][0];
#pragma unroll
            for (int mt = 0; mt < 2; ++mt)
#pragma unroll
                for (int nt = 0; nt < 4; ++nt)
                    acc[mt][nt] = __builtin_amdgcn_mfma_f32_16x16x32_bf16(af[mt], bfr[nt], acc[mt][nt], 0, 0, 0);
        }
    }

    int p0 = offs[o] + m0;
    float bv[4];
#pragma unroll
    for (int nt = 0; nt < 4; ++nt) bv[nt] = bias2[o * Hn + n0 + wn + nt * 16 + l15];
#pragma unroll
    for (int mt = 0; mt < 2; ++mt)
#pragma unroll
        for (int r = 0; r < 4; ++r) {
            int rowl = wm + mt * 16 + kg * 4 + r;
            int b = sidx_pad[p0 + rowl];
            if (b >= 0) {
                float* orow = out + (size_t)b * Hn + n0 + wn + l15;
#pragma unroll
                for (int nt = 0; nt < 4; ++nt) {
                    float v = acc[mt][nt][r] + bv[nt];
                    orow[nt * 16] = v > 0.f ? v : 0.f;
                }
            }
        }
}

extern "C" void kernel_launch(void* const* d_in, const int* in_sizes, int n_in,
                              void* d_out, int out_size, void* d_ws, size_t ws_size,
                              hipStream_t stream) {
    const float* x      = (const float*)d_in[0];
    const int*   op_idx = (const int*)d_in[1];
    const float* W1     = (const float*)d_in[2];
    const float* bias1  = (const float*)d_in[3];
    const float* W2     = (const float*)d_in[4];
    const float* bias2  = (const float*)d_in[5];
    float* out = (float*)d_out;

    char* ws = (char*)d_ws;
    int* offs      = (int*)ws;                                  // 40 ints
    int* sidx_pad  = (int*)(ws + 1024);                         // 20 KB
    unsigned short* xs  = (unsigned short*)(ws + 65536);        // 10 MB tiled
    unsigned short* h1T = (unsigned short*)(ws + 65536 + 10485760);   // 10 MB tiled
    unsigned short* Wt  = (unsigned short*)(ws + 65536 + 20971520);   // 32 MB tiled

    // K1: W1 transpose->tiled + bucket (fused z-slice)
    hipLaunchKernelGGL(wtrans_kernel, dim3(16, 16, On + 1), dim3(256), 0, stream,
                       W1, Wt, op_idx, sidx_pad, offs);
    // K2: gather+cvt x -> tiled
    hipLaunchKernelGGL(xprep_kernel, dim3(MT), dim3(256), 0, stream,
                       x, sidx_pad, offs, xs);
    // K3: layer-1 GEMM
    dim3 grid(8, 64, On);
    hipLaunchKernelGGL(gemm1_kernel, grid, dim3(256), 0, stream,
                       xs, Wt, bias1, offs, h1T);
    // K4: W2 transpose->tiled (reuses Wt)
    hipLaunchKernelGGL(wtrans_kernel, dim3(16, 16, On), dim3(256), 0, stream,
                       W2, Wt, op_idx, sidx_pad, offs);
    // K5: layer-2 GEMM
    hipLaunchKernelGGL(gemm2_kernel, grid, dim3(256), 0, stream,
                       h1T, Wt, bias2, sidx_pad, offs, out);
}